// Round 1
// baseline (168.693 us; speedup 1.0000x reference)
//
#include <hip/hip_runtime.h>
#include <math.h>

// Problem constants
#define LL 4096      // H*W
#define KK 256       // C
#define HH 64
#define WW 64
#define NHEAD 8
#define NPNT 16
#define HD 32        // C / NH

// ---------------------------------------------------------------------------
// Generic tiled f32 GEMM: out[b][o][l] = sum_k A * W[o][k] (+bias) epilogues.
// ATRANS==0: A is (B, K, L) channel-major (feat-like)
// ATRANS==1: A is (B, L, K) pixel-major (pre-like)
// STORE==0: out[((b*OB + o_off + o))*L + l] = acc + bias[o]      (raw proj)
// STORE==1: mem2 layout out[((b*8 + o>>5)*L + l)*32 + (o&31)] = acc + bias[o]
// STORE==2: out[((b*OB + o))*L + l] = acc * (bias[o]/sqrt(1+eps)) + p2[o]
// Tile: 64 pixels x 64 outputs, KC=32, 256 threads, 4x4 accs per thread.
// ---------------------------------------------------------------------------
template<int ATRANS, int STORE>
__global__ __launch_bounds__(256) void gemm_k(
    const float* __restrict__ A,
    const float* __restrict__ W,
    const float* __restrict__ bias,   // gamma for STORE==2
    const float* __restrict__ p2,     // beta for STORE==2
    float* __restrict__ out,
    int O, int OB, int o_off)
{
    __shared__ float As[32][68];   // [k][px], pad 68 -> float4-aligned rows
    __shared__ float Ws[32][68];   // [k][o]

    const int tid = threadIdx.x;
    const int b  = blockIdx.z;
    const int l0 = blockIdx.x * 64;
    const int o0 = blockIdx.y * 64;

    const int px_sub = (tid & 15) * 4;
    const int o_sub  = (tid >> 4) * 4;

    float acc[4][4] = {};

    for (int k0 = 0; k0 < KK; k0 += 32) {
        // ---- stage A tile (32 k x 64 px) ----
        if (ATRANS == 0) {
            const int k  = tid >> 3;         // 0..31
            const int px = (tid & 7) * 8;    // 0..56 step 8
            const float* src = A + ((size_t)(b * KK + k0 + k)) * LL + l0 + px;
            float4 v0 = *(const float4*)(src);
            float4 v1 = *(const float4*)(src + 4);
            *(float4*)&As[k][px]     = v0;
            *(float4*)&As[k][px + 4] = v1;
        } else {
            const int px = tid >> 2;         // 0..63
            const int kq = (tid & 3) * 8;    // 0,8,16,24
            const float* src = A + ((size_t)(b * LL + l0 + px)) * KK + k0 + kq;
            float4 v0 = *(const float4*)(src);
            float4 v1 = *(const float4*)(src + 4);
            As[kq + 0][px] = v0.x; As[kq + 1][px] = v0.y;
            As[kq + 2][px] = v0.z; As[kq + 3][px] = v0.w;
            As[kq + 4][px] = v1.x; As[kq + 5][px] = v1.y;
            As[kq + 6][px] = v1.z; As[kq + 7][px] = v1.w;
        }
        // ---- stage W tile (32 k x 64 o), transposed into [k][o] ----
        {
            const int o  = tid >> 2;         // 0..63
            const int kq = (tid & 3) * 8;
            int oc = o0 + o; if (oc >= O) oc = O - 1;   // clamp; dup rows masked at store
            const float* src = W + (size_t)oc * KK + k0 + kq;
            float4 v0 = *(const float4*)(src);
            float4 v1 = *(const float4*)(src + 4);
            Ws[kq + 0][o] = v0.x; Ws[kq + 1][o] = v0.y;
            Ws[kq + 2][o] = v0.z; Ws[kq + 3][o] = v0.w;
            Ws[kq + 4][o] = v1.x; Ws[kq + 5][o] = v1.y;
            Ws[kq + 6][o] = v1.z; Ws[kq + 7][o] = v1.w;
        }
        __syncthreads();

        #pragma unroll
        for (int kk = 0; kk < 32; ++kk) {
            float4 a4 = *(const float4*)&As[kk][px_sub];
            float4 w4 = *(const float4*)&Ws[kk][o_sub];
            float av[4] = {a4.x, a4.y, a4.z, a4.w};
            float wv[4] = {w4.x, w4.y, w4.z, w4.w};
            #pragma unroll
            for (int i = 0; i < 4; ++i)
                #pragma unroll
                for (int j = 0; j < 4; ++j)
                    acc[i][j] += av[i] * wv[j];
        }
        __syncthreads();
    }

    // ---- store ----
    #pragma unroll
    for (int i = 0; i < 4; ++i) {
        const int l = l0 + px_sub + i;
        #pragma unroll
        for (int j = 0; j < 4; ++j) {
            const int o = o0 + o_sub + j;
            if (STORE == 1) {
                out[((size_t)(b * NHEAD + (o >> 5)) * LL + l) * HD + (o & 31)] =
                    acc[i][j] + bias[o];
            } else if (STORE == 0) {
                if (o < O)
                    out[((size_t)(b * OB + o_off + o)) * LL + l] =
                        acc[i][j] + (bias ? bias[o] : 0.f);
            } else {
                const float sc = bias[o] / sqrtf(1.f + 1e-5f);
                out[((size_t)(b * OB + o)) * LL + l] = acc[i][j] * sc + p2[o];
            }
        }
    }
}

// ---------------------------------------------------------------------------
// Sampling: one 32-lane group per (b, h, l); lane = d (head channel).
// Reads raw projections (B,400,L): [0,16) size, [16,272) offset, [272,400) att.
// memory in mem2 (B, NH, L, HD) so each bilinear tap is 32 contiguous floats.
// Writes pre (B, L, C) pixel-major for the out-proj GEMM.
// ---------------------------------------------------------------------------
__global__ __launch_bounds__(256) void sample_k(
    const float* __restrict__ mem2,
    const float* __restrict__ raw,
    float* __restrict__ pre)
{
    const int g = blockIdx.x * 8 + (threadIdx.x >> 5);  // 0 .. B*NH*L-1
    const int d = threadIdx.x & 31;
    const int l = g & (LL - 1);
    const int h = (g >> 12) & (NHEAD - 1);
    const int b = g >> 15;

    const float* rb = raw + (size_t)b * 400 * LL;

    // attention softmax over NP=16 (all lanes redundantly; broadcast loads)
    float logit[NPNT];
    float m = -1e30f;
    #pragma unroll
    for (int p = 0; p < NPNT; ++p) {
        logit[p] = rb[(size_t)(272 + h * NPNT + p) * LL + l];
        m = fmaxf(m, logit[p]);
    }
    float ssum = 0.f;
    #pragma unroll
    for (int p = 0; p < NPNT; ++p) {
        logit[p] = __expf(logit[p] - m);
        ssum += logit[p];
    }
    const float inv = 1.f / ssum;

    // size (sigmoid + clip)
    float s0 = rb[(size_t)(h * 2 + 0) * LL + l];
    float s1 = rb[(size_t)(h * 2 + 1) * LL + l];
    s0 = fminf(fmaxf(1.f / (1.f + __expf(-s0)), 0.25f), 0.75f);
    s1 = fminf(fmaxf(1.f / (1.f + __expf(-s1)), 0.25f), 0.75f);

    const int xl = l & (WW - 1);
    const int yl = l >> 6;
    const float cx = ((float)xl + 0.5f) / ((float)WW + 1e-6f);
    const float cy = ((float)yl + 0.5f) / ((float)HH + 1e-6f);

    const float* mb = mem2 + (size_t)(b * NHEAD + h) * LL * HD;

    float acc = 0.f;
    #pragma unroll
    for (int p = 0; p < NPNT; ++p) {
        float o0 = rb[(size_t)(16 + (h * NPNT + p) * 2 + 0) * LL + l];
        float o1 = rb[(size_t)(16 + (h * NPNT + p) * 2 + 1) * LL + l];
        o0 = 1.f / (1.f + __expf(-o0));
        o1 = 1.f / (1.f + __expf(-o1));
        float gx = cx - 0.5f * s0 + o0 * s0;
        float gy = cy - 0.5f * s1 + o1 * s1;
        gx = fminf(fmaxf(gx, 0.f), 1.f);
        gy = fminf(fmaxf(gy, 0.f), 1.f);
        const float ix = gx * (float)(WW - 1);
        const float iy = gy * (float)(HH - 1);
        const float x0f = floorf(ix);
        const float y0f = floorf(iy);
        const float wx = ix - x0f;
        const float wy = iy - y0f;
        int x0 = (int)x0f; x0 = min(max(x0, 0), WW - 1);
        int x1 = min(x0 + 1, WW - 1);
        int y0 = (int)y0f; y0 = min(max(y0, 0), HH - 1);
        int y1 = min(y0 + 1, HH - 1);

        const float g00 = mb[(size_t)(y0 * WW + x0) * HD + d];
        const float g01 = mb[(size_t)(y0 * WW + x1) * HD + d];
        const float g10 = mb[(size_t)(y1 * WW + x0) * HD + d];
        const float g11 = mb[(size_t)(y1 * WW + x1) * HD + d];

        const float wp = logit[p] * inv;
        acc += wp * ((1.f - wx) * (1.f - wy) * g00 + wx * (1.f - wy) * g01 +
                     (1.f - wx) * wy * g10 + wx * wy * g11);
    }

    pre[((size_t)b * LL + l) * KK + h * HD + d] = acc;
}

extern "C" void kernel_launch(void* const* d_in, const int* in_sizes, int n_in,
                              void* d_out, int out_size, void* d_ws, size_t ws_size,
                              hipStream_t stream) {
    const float* feat  = (const float*)d_in[0];
    const float* vw    = (const float*)d_in[1];
    const float* vb    = (const float*)d_in[2];
    const float* sw    = (const float*)d_in[3];
    const float* sb    = (const float*)d_in[4];
    const float* adw   = (const float*)d_in[5];
    const float* adb   = (const float*)d_in[6];
    const float* atw   = (const float*)d_in[7];
    const float* atb   = (const float*)d_in[8];
    const float* pw    = (const float*)d_in[9];
    const float* gamma = (const float*)d_in[10];
    const float* beta  = (const float*)d_in[11];
    float* out = (float*)d_out;
    float* ws  = (float*)d_ws;

    float* mem2 = ws;                        // B*NH*L*HD   = 2,097,152 f
    float* raw  = ws + 2097152;              // B*400*L     = 3,276,800 f
    float* pre  = raw + 3276800;             // B*L*C       = 2,097,152 f

    const dim3 blk(256);
    // value projection -> mem2 (B, NH, L, HD)
    gemm_k<0, 1><<<dim3(64, 4, 2), blk, 0, stream>>>(feat, vw, vb, nullptr, mem2, 256, 0, 0);
    // size projection -> raw ch [0,16)
    gemm_k<0, 0><<<dim3(64, 1, 2), blk, 0, stream>>>(feat, sw, sb, nullptr, raw, 16, 400, 0);
    // anchor offset projection -> raw ch [16,272)
    gemm_k<0, 0><<<dim3(64, 4, 2), blk, 0, stream>>>(feat, adw, adb, nullptr, raw, 256, 400, 16);
    // attention projection -> raw ch [272,400)
    gemm_k<0, 0><<<dim3(64, 2, 2), blk, 0, stream>>>(feat, atw, atb, nullptr, raw, 128, 400, 272);
    // bilinear sampling + attention-weighted sum -> pre (B, L, C)
    sample_k<<<dim3(8192), blk, 0, stream>>>(mem2, raw, pre);
    // out projection + BN -> d_out (B, C, H, W)
    gemm_k<1, 2><<<dim3(64, 4, 2), blk, 0, stream>>>(pre, pw, gamma, beta, out, 256, 256, 0);
}